// Round 8
// baseline (242.472 us; speedup 1.0000x reference)
//
#include <hip/hip_runtime.h>
#include <hip/hip_bf16.h>

typedef short s16x8 __attribute__((ext_vector_type(8)));
typedef short s16x4 __attribute__((ext_vector_type(4)));
typedef float f32x4 __attribute__((ext_vector_type(4)));
typedef __hip_bfloat16 bf16;

#define MFMA16(a, b, c) __builtin_amdgcn_mfma_f32_16x16x32_bf16((a), (b), (c), 0, 0, 0)

#define BATCH 4
#define SEQ 2048
#define NH 12
#define DH 64
#define DM 768
#define ROWS (BATCH * SEQ)       // 8192
#define QKVC (3 * DM)            // 2304
#define LOG2E 1.4426950408889634f

static __device__ inline float fast_exp2(float x) {
  float r;
  asm("v_exp_f32 %0, %1" : "=v"(r) : "v"(x));
  return r;
}
static __device__ inline unsigned pkbf16(float a, float b) {
  bf16 ha = __float2bfloat16(a), hb = __float2bfloat16(b);
  unsigned short ua, ub;
  __builtin_memcpy(&ua, &ha, 2);
  __builtin_memcpy(&ub, &hb, 2);
  return (unsigned)ua | ((unsigned)ub << 16);
}

// async global->LDS 16B copy (m97 pattern; dest must be lane-linear)
typedef __attribute__((address_space(3))) unsigned int lds_u32;
typedef __attribute__((address_space(1))) const unsigned int glb_u32;
static __device__ inline void gl2lds16(const void* g, void* l) {
  __builtin_amdgcn_global_load_lds((glb_u32*)g, (lds_u32*)l, 16, 0, 0);
}

// ---------------------------------------------------------------------------
// Kernel 1: fused prep, all-coalesced via 4x4 in-register transpose.
//  Region A (36 blocks):  W{q,k,v}[n][e][h] -> WcT[(mat,n,h)][e] bf16
//  Region B (12 blocks):  wo[r][e] -> WoT[e][r] bf16
//  Region C (1536 blocks): x fp32 -> bf16
// ---------------------------------------------------------------------------
#define PREP_A 36
#define PREP_B (PREP_A + 12)
#define PREP_C (PREP_B + 1536)
__global__ __launch_bounds__(256) void prep_all(
    const float* __restrict__ wq, const float* __restrict__ wk,
    const float* __restrict__ wv, const float* __restrict__ wo,
    const float* __restrict__ x, bf16* __restrict__ WcT,
    bf16* __restrict__ WoT, bf16* __restrict__ xb) {
  const int bid = blockIdx.x;
  const int tid = threadIdx.x;
  if (bid < PREP_A) {
    // one (mat, n) slice: 768e x 64h -> rows [h][768e]
    const int mat = bid / 12, n = bid % 12;
    const float* Wsrc =
        ((mat == 0) ? wq : (mat == 1) ? wk : wv) + (size_t)n * DM * DH;
    bf16* dst = WcT + ((size_t)mat * DM + n * DH) * DM;
    const int h4 = (tid & 15) * 4;
    for (int it = 0; it < 12; it++) {
      int e4 = (it * 16 + (tid >> 4)) * 4;
      float4 v0 = *(const float4*)(Wsrc + (size_t)(e4 + 0) * DH + h4);
      float4 v1 = *(const float4*)(Wsrc + (size_t)(e4 + 1) * DH + h4);
      float4 v2 = *(const float4*)(Wsrc + (size_t)(e4 + 2) * DH + h4);
      float4 v3 = *(const float4*)(Wsrc + (size_t)(e4 + 3) * DH + h4);
      const float* c0 = (const float*)&v0;
      const float* c1 = (const float*)&v1;
      const float* c2 = (const float*)&v2;
      const float* c3 = (const float*)&v3;
      for (int j = 0; j < 4; j++) {
        uint2 w;
        w.x = pkbf16(c0[j], c1[j]);
        w.y = pkbf16(c2[j], c3[j]);
        *(uint2*)(dst + (size_t)(h4 + j) * DM + e4) = w;
      }
    }
  } else if (bid < PREP_B) {
    // wo 768r x 768e -> WoT[e][r]; block owns 64 r
    const int r0 = (bid - PREP_A) * 64;
    const int r4 = r0 + (tid >> 4) * 4;
    for (int it = 0; it < 12; it++) {
      int e4 = it * 64 + (tid & 15) * 4;
      float4 v0 = *(const float4*)(wo + (size_t)(r4 + 0) * DM + e4);
      float4 v1 = *(const float4*)(wo + (size_t)(r4 + 1) * DM + e4);
      float4 v2 = *(const float4*)(wo + (size_t)(r4 + 2) * DM + e4);
      float4 v3 = *(const float4*)(wo + (size_t)(r4 + 3) * DM + e4);
      const float* c0 = (const float*)&v0;
      const float* c1 = (const float*)&v1;
      const float* c2 = (const float*)&v2;
      const float* c3 = (const float*)&v3;
      for (int j = 0; j < 4; j++) {
        uint2 w;
        w.x = pkbf16(c0[j], c1[j]);
        w.y = pkbf16(c2[j], c3[j]);
        *(uint2*)(WoT + (size_t)(e4 + j) * DM + r4) = w;
      }
    }
  } else {
    // x fp32 -> bf16; 2 chunks of 8 per thread
    for (int u = 0; u < 2; u++) {
      size_t j = (size_t)(bid - PREP_B) * 512 + tid + u * 256;
      const float* src = x + j * 8;
      float4 f0 = *(const float4*)src;
      float4 f1 = *(const float4*)(src + 4);
      bf16 tmp[8];
      tmp[0] = __float2bfloat16(f0.x); tmp[1] = __float2bfloat16(f0.y);
      tmp[2] = __float2bfloat16(f0.z); tmp[3] = __float2bfloat16(f0.w);
      tmp[4] = __float2bfloat16(f1.x); tmp[5] = __float2bfloat16(f1.y);
      tmp[6] = __float2bfloat16(f1.z); tmp[7] = __float2bfloat16(f1.w);
      *(s16x8*)(xb + j * 8) = *(const s16x8*)tmp;
    }
  }
}

// ---------------------------------------------------------------------------
// Kernel 2: QKV projection GEMM, m97 config: 128x128 tile, BK=64, async stage.
// Outputs: Qb [bh][s][64] (scaled 0.125*log2e), Kb [bh][s][64], Vt [bh][h][s].
// ---------------------------------------------------------------------------
__global__ __launch_bounds__(256) void qkv_gemm(
    const bf16* __restrict__ xb, const bf16* __restrict__ WcT,
    const float* __restrict__ bQ, const float* __restrict__ bK,
    const float* __restrict__ bV, bf16* __restrict__ Qb,
    bf16* __restrict__ Kb, bf16* __restrict__ Vt) {
  __shared__ bf16 As[128 * 64];
  __shared__ bf16 Bs[128 * 64];
  const int m0 = blockIdx.x * 128;
  const int n0 = blockIdx.y * 128;
  const int tid = threadIdx.x;
  const int wave = tid >> 6, lane = tid & 63;
  const int quad = lane >> 4, l15 = lane & 15;
  const int wm = (wave & 1) * 64, wn = (wave >> 1) * 64;

  f32x4 acc[4][4] = {};

  for (int k0 = 0; k0 < DM; k0 += 64) {
    for (int u = 0; u < 4; u++) {
      int c = tid + u * 256;                 // 1024 chunks of 16B per matrix
      int row = c >> 3, sg = (c & 7) << 3;
      gl2lds16(xb + (size_t)(m0 + row) * DM + k0 + sg, &As[c * 8]);
      gl2lds16(WcT + (size_t)(n0 + row) * DM + k0 + sg, &Bs[c * 8]);
    }
    __syncthreads();
    for (int ks = 0; ks < 2; ks++) {
      s16x8 af[4], bfr[4];
      for (int i = 0; i < 4; i++)
        af[i] = *(const s16x8*)&As[(wm + i * 16 + l15) * 64 + ks * 32 + quad * 8];
      for (int j = 0; j < 4; j++)
        bfr[j] = *(const s16x8*)&Bs[(wn + j * 16 + l15) * 64 + ks * 32 + quad * 8];
      for (int i = 0; i < 4; i++)
        for (int j = 0; j < 4; j++)
          acc[i][j] = MFMA16(af[i], bfr[j], acc[i][j]);
    }
    __syncthreads();
  }

  const int mat = n0 / DM;  // uniform per block (768 % 128 == 0)
  for (int j = 0; j < 4; j++) {
    int col = n0 + wn + j * 16 + l15;
    int cc = col - mat * DM;
    int head = cc >> 6, h = cc & 63;
    float bsv = ((mat == 0) ? bQ : (mat == 1) ? bK : bV)[cc];
    for (int i = 0; i < 4; i++) {
      int row0 = m0 + wm + i * 16 + quad * 4;
      int b = row0 >> 11;
      int s = row0 & 2047;
      int bh = b * NH + head;
      if (mat == 2) {
        s16x4 pv;
        for (int r = 0; r < 4; r++) {
          bf16 hv = __float2bfloat16(acc[i][j][r] + bsv);
          short sv; __builtin_memcpy(&sv, &hv, 2);
          pv[r] = sv;
        }
        *(s16x4*)(Vt + ((size_t)bh * DH + h) * SEQ + s) = pv;
      } else {
        const float scale = (mat == 0) ? (0.125f * LOG2E) : 1.0f;
        bf16* dst = ((mat == 0) ? Qb : Kb) + ((size_t)bh * SEQ + s) * DH + h;
        for (int r = 0; r < 4; r++)
          dst[(size_t)r * DH] = __float2bfloat16((acc[i][j][r] + bsv) * scale);
      }
    }
  }
}

// ---------------------------------------------------------------------------
// Kernel 3: flash attention (causal) — unchanged round-7 version.
// Balanced-pair blocks, 4 waves x 16 q, async padded double-buffer staging.
// ---------------------------------------------------------------------------
__global__ __launch_bounds__(256) void flash_kernel(
    const bf16* __restrict__ Qb, const bf16* __restrict__ Kb,
    const bf16* __restrict__ Vt, bf16* __restrict__ Z) {
  __shared__ bf16 Ks[2][64 * 72];   // [key][h], stride 72
  __shared__ bf16 VsT[2][64 * 72];  // [h][key], stride 72
  __shared__ bf16 Ps[4][16 * 72];   // per-wave P [q][key], stride 72

  const int bh = blockIdx.x >> 4;  // 0..47
  const int p = blockIdx.x & 15;   // 0..15
  const int qtA = 31 - p, qtB = p;
  const int b = bh / NH, head = bh % NH;
  const int tid = threadIdx.x;
  const int wave = tid >> 6, lane = tid & 63;
  const int quad = lane >> 4, l15 = lane & 15;
  const int qwA = qtA * 64 + wave * 16;
  const int qwB = qtB * 64 + wave * 16;

  const bf16* Kbase = Kb + (size_t)bh * SEQ * DH;
  const bf16* Vbase = Vt + (size_t)bh * DH * SEQ;

  s16x8 bqA[2], bqB[2];
  for (int ks = 0; ks < 2; ks++) {
    bqA[ks] = *(const s16x8*)(Qb +
        ((size_t)bh * SEQ + qwA + l15) * DH + ks * 32 + quad * 8);
    bqB[ks] = *(const s16x8*)(Qb +
        ((size_t)bh * SEQ + qwB + l15) * DH + ks * 32 + quad * 8);
  }

  f32x4 oA[4] = {}, oB[4] = {};
  float lA = 0.f, lB = 0.f;

  // 576 16B chunks per matrix (9 per 64-elem row; chunk 8 dups chunk 0 into
  // the pad). dest = c*16B lane-linear -> LDS stride 72, conflict-free reads.
  auto stage_tile = [&](int kt, int buf) {
    const int kbase = kt * 64;
    for (int u = 0; u < 3; u++) {
      int c = tid + u * 256;
      if (c < 576) {
        int row = c / 9;
        int i = c - row * 9;
        int off = (i & 7) << 3;
        gl2lds16(Kbase + (size_t)(kbase + row) * DH + off, &Ks[buf][c * 8]);
        gl2lds16(Vbase + (size_t)row * SEQ + kbase + off, &VsT[buf][c * 8]);
      }
    }
  };

  auto compute = [&](int kt, int buf, const s16x8 bq[2], f32x4 o[4],
                     float& l_i, int qw, bool diag) {
    const int kbase = kt * 64;
    f32x4 s[4] = {};
    for (int ks = 0; ks < 2; ks++) {
      s16x8 ak[4];
      for (int ktf = 0; ktf < 4; ktf++)
        ak[ktf] =
            *(const s16x8*)&Ks[buf][(ktf * 16 + l15) * 72 + ks * 32 + quad * 8];
      for (int ktf = 0; ktf < 4; ktf++)
        s[ktf] = MFMA16(ak[ktf], bq[ks], s[ktf]);
    }

    if (diag) {
      int qg = qw + l15;
      for (int ktf = 0; ktf < 4; ktf++)
        for (int r = 0; r < 4; r++) {
          int kg = kbase + ktf * 16 + quad * 4 + r;
          if (kg > qg) s[ktf][r] = -1e30f;
        }
    }

    float rs = 0.f;
    for (int ktf = 0; ktf < 4; ktf++)
      for (int r = 0; r < 4; r++) {
        float pv = fast_exp2(s[ktf][r]);
        s[ktf][r] = pv;
        rs += pv;
      }
    l_i += rs;

    bf16* Pw = Ps[wave];
    for (int ktf = 0; ktf < 4; ktf++) {
      uint2 w;
      w.x = pkbf16(s[ktf][0], s[ktf][1]);
      w.y = pkbf16(s[ktf][2], s[ktf][3]);
      *(uint2*)&Pw[l15 * 72 + ktf * 16 + quad * 4] = w;
    }
    asm volatile("s_waitcnt lgkmcnt(0)" ::: "memory");

    for (int ks2 = 0; ks2 < 2; ks2++) {
      s16x8 ap = *(const s16x8*)&Pw[l15 * 72 + ks2 * 32 + quad * 8];
      for (int hf = 0; hf < 4; hf++) {
        s16x8 bv =
            *(const s16x8*)&VsT[buf][(hf * 16 + l15) * 72 + ks2 * 32 + quad * 8];
        o[hf] = MFMA16(ap, bv, o[hf]);
      }
    }
  };

  stage_tile(0, 0);
  for (int kt = 0; kt <= qtA; kt++) {
    const int cur = kt & 1;
    __syncthreads();
    if (kt < qtA) stage_tile(kt + 1, cur ^ 1);
    compute(kt, cur, bqA, oA, lA, qwA, kt == qtA);
    if (kt <= qtB) compute(kt, cur, bqB, oB, lB, qwB, kt == qtB);
  }

  auto epilogue = [&](f32x4 o[4], float l_i, int qw) {
    float lv = l_i;
    lv += __shfl_xor(lv, 16, 64);
    lv += __shfl_xor(lv, 32, 64);
    float linv = 1.f / lv;
    for (int r = 0; r < 4; r++) {
      float li = __shfl(linv, (lane & 48) | (quad * 4 + r), 64);
      int q = qw + quad * 4 + r;
      for (int hf = 0; hf < 4; hf++) {
        Z[((size_t)b * SEQ + q) * DM + head * DH + hf * 16 + l15] =
            __float2bfloat16(o[hf][r] * li);
      }
    }
  };
  epilogue(oA, lA, qwA);
  epilogue(oB, lB, qwB);
}

// ---------------------------------------------------------------------------
// Kernel 4: output projection (round-5 config: 128x128, BK=32).
// ---------------------------------------------------------------------------
__global__ __launch_bounds__(256) void out_gemm(
    const bf16* __restrict__ Z, const bf16* __restrict__ WoT,
    const float* __restrict__ bO, float* __restrict__ out) {
  __shared__ bf16 As[128 * 32];
  __shared__ bf16 Bs[128 * 32];
  const int m0 = blockIdx.x * 128;
  const int n0 = blockIdx.y * 128;
  const int tid = threadIdx.x;
  const int wave = tid >> 6, lane = tid & 63;
  const int quad = lane >> 4, l15 = lane & 15;
  const int wm = (wave & 1) * 64, wn = (wave >> 1) * 64;

  f32x4 acc[4][4] = {};

  for (int k0 = 0; k0 < DM; k0 += 32) {
    {
      int c = tid, row = c >> 2, sg = (c & 3) << 3;
      gl2lds16(Z + (size_t)(m0 + row) * DM + k0 + sg, &As[c * 8]);
      gl2lds16(WoT + (size_t)(n0 + row) * DM + k0 + sg, &Bs[c * 8]);
      c = tid + 256; row = c >> 2; sg = (c & 3) << 3;
      gl2lds16(Z + (size_t)(m0 + row) * DM + k0 + sg, &As[c * 8]);
      gl2lds16(WoT + (size_t)(n0 + row) * DM + k0 + sg, &Bs[c * 8]);
    }
    __syncthreads();
    s16x8 af[4], bfr[4];
    for (int i = 0; i < 4; i++)
      af[i] = *(const s16x8*)&As[(wm + i * 16 + l15) * 32 + quad * 8];
    for (int j = 0; j < 4; j++)
      bfr[j] = *(const s16x8*)&Bs[(wn + j * 16 + l15) * 32 + quad * 8];
    for (int i = 0; i < 4; i++)
      for (int j = 0; j < 4; j++)
        acc[i][j] = MFMA16(af[i], bfr[j], acc[i][j]);
    __syncthreads();
  }

  for (int j = 0; j < 4; j++) {
    int col = n0 + wn + j * 16 + l15;
    float bv = bO[col];
    for (int i = 0; i < 4; i++)
      for (int r = 0; r < 4; r++) {
        int row = m0 + wm + i * 16 + quad * 4 + r;
        out[(size_t)row * DM + col] = acc[i][j][r] + bv;
      }
  }
}

// ---------------------------------------------------------------------------
extern "C" void kernel_launch(void* const* d_in, const int* in_sizes, int n_in,
                              void* d_out, int out_size, void* d_ws,
                              size_t ws_size, hipStream_t stream) {
  const float* x  = (const float*)d_in[0];
  const float* wq = (const float*)d_in[1];
  const float* wk = (const float*)d_in[2];
  const float* wv = (const float*)d_in[3];
  const float* wo = (const float*)d_in[4];
  const float* bq = (const float*)d_in[5];
  const float* bk = (const float*)d_in[6];
  const float* bv = (const float*)d_in[7];
  const float* bo = (const float*)d_in[8];
  float* out = (float*)d_out;

  bf16* WcT = (bf16*)d_ws;                    // 2304*768
  bf16* WoT = WcT + (size_t)QKVC * DM;        //  768*768
  bf16* Qb  = WoT + (size_t)DM * DM;          // 8192*768
  bf16* Kb  = Qb + (size_t)ROWS * DM;         // 8192*768
  bf16* Vt  = Kb + (size_t)ROWS * DM;         // 8192*768 ([bh][h][s])
  bf16* xbZ = Vt + (size_t)ROWS * DM;         // 8192*768 (xb, then Z)

  prep_all<<<PREP_C, 256, 0, stream>>>(wq, wk, wv, wo, x, WcT, WoT, xbZ);
  qkv_gemm<<<dim3(ROWS / 128, QKVC / 128), 256, 0, stream>>>(
      xbZ, WcT, bq, bk, bv, Qb, Kb, Vt);
  flash_kernel<<<48 * 16, 256, 0, stream>>>(Qb, Kb, Vt, xbZ);
  out_gemm<<<dim3(ROWS / 128, DM / 128), 256, 0, stream>>>(xbZ, WoT, bo, out);
}

// Round 9
// 234.603 us; speedup vs baseline: 1.0335x; 1.0335x over previous
//
#include <hip/hip_runtime.h>
#include <hip/hip_bf16.h>

typedef short s16x8 __attribute__((ext_vector_type(8)));
typedef short s16x4 __attribute__((ext_vector_type(4)));
typedef float f32x4 __attribute__((ext_vector_type(4)));
typedef __hip_bfloat16 bf16;

#define MFMA16(a, b, c) __builtin_amdgcn_mfma_f32_16x16x32_bf16((a), (b), (c), 0, 0, 0)

#define BATCH 4
#define SEQ 2048
#define NH 12
#define DH 64
#define DM 768
#define ROWS (BATCH * SEQ)       // 8192
#define QKVC (3 * DM)            // 2304
#define LOG2E 1.4426950408889634f

static __device__ inline float fast_exp2(float x) {
  float r;
  asm("v_exp_f32 %0, %1" : "=v"(r) : "v"(x));
  return r;
}
static __device__ inline unsigned pkbf16(float a, float b) {
  bf16 ha = __float2bfloat16(a), hb = __float2bfloat16(b);
  unsigned short ua, ub;
  __builtin_memcpy(&ua, &ha, 2);
  __builtin_memcpy(&ub, &hb, 2);
  return (unsigned)ua | ((unsigned)ub << 16);
}

// async global->LDS 16B copy (m97 pattern; dest must be lane-linear)
typedef __attribute__((address_space(3))) unsigned int lds_u32;
typedef __attribute__((address_space(1))) const unsigned int glb_u32;
static __device__ inline void gl2lds16(const void* g, void* l) {
  __builtin_amdgcn_global_load_lds((glb_u32*)g, (lds_u32*)l, 16, 0, 0);
}

// ---------------------------------------------------------------------------
// Kernel 1: fused prep, all-coalesced via 4x4 in-register transpose.
// ---------------------------------------------------------------------------
#define PREP_A 36
#define PREP_B (PREP_A + 12)
#define PREP_C (PREP_B + 1536)
__global__ __launch_bounds__(256) void prep_all(
    const float* __restrict__ wq, const float* __restrict__ wk,
    const float* __restrict__ wv, const float* __restrict__ wo,
    const float* __restrict__ x, bf16* __restrict__ WcT,
    bf16* __restrict__ WoT, bf16* __restrict__ xb) {
  const int bid = blockIdx.x;
  const int tid = threadIdx.x;
  if (bid < PREP_A) {
    const int mat = bid / 12, n = bid % 12;
    const float* Wsrc =
        ((mat == 0) ? wq : (mat == 1) ? wk : wv) + (size_t)n * DM * DH;
    bf16* dst = WcT + ((size_t)mat * DM + n * DH) * DM;
    const int h4 = (tid & 15) * 4;
    for (int it = 0; it < 12; it++) {
      int e4 = (it * 16 + (tid >> 4)) * 4;
      float4 v0 = *(const float4*)(Wsrc + (size_t)(e4 + 0) * DH + h4);
      float4 v1 = *(const float4*)(Wsrc + (size_t)(e4 + 1) * DH + h4);
      float4 v2 = *(const float4*)(Wsrc + (size_t)(e4 + 2) * DH + h4);
      float4 v3 = *(const float4*)(Wsrc + (size_t)(e4 + 3) * DH + h4);
      const float* c0 = (const float*)&v0;
      const float* c1 = (const float*)&v1;
      const float* c2 = (const float*)&v2;
      const float* c3 = (const float*)&v3;
      for (int j = 0; j < 4; j++) {
        uint2 w;
        w.x = pkbf16(c0[j], c1[j]);
        w.y = pkbf16(c2[j], c3[j]);
        *(uint2*)(dst + (size_t)(h4 + j) * DM + e4) = w;
      }
    }
  } else if (bid < PREP_B) {
    const int r0 = (bid - PREP_A) * 64;
    const int r4 = r0 + (tid >> 4) * 4;
    for (int it = 0; it < 12; it++) {
      int e4 = it * 64 + (tid & 15) * 4;
      float4 v0 = *(const float4*)(wo + (size_t)(r4 + 0) * DM + e4);
      float4 v1 = *(const float4*)(wo + (size_t)(r4 + 1) * DM + e4);
      float4 v2 = *(const float4*)(wo + (size_t)(r4 + 2) * DM + e4);
      float4 v3 = *(const float4*)(wo + (size_t)(r4 + 3) * DM + e4);
      const float* c0 = (const float*)&v0;
      const float* c1 = (const float*)&v1;
      const float* c2 = (const float*)&v2;
      const float* c3 = (const float*)&v3;
      for (int j = 0; j < 4; j++) {
        uint2 w;
        w.x = pkbf16(c0[j], c1[j]);
        w.y = pkbf16(c2[j], c3[j]);
        *(uint2*)(WoT + (size_t)(e4 + j) * DM + r4) = w;
      }
    }
  } else {
    for (int u = 0; u < 2; u++) {
      size_t j = (size_t)(bid - PREP_B) * 512 + tid + u * 256;
      const float* src = x + j * 8;
      float4 f0 = *(const float4*)src;
      float4 f1 = *(const float4*)(src + 4);
      bf16 tmp[8];
      tmp[0] = __float2bfloat16(f0.x); tmp[1] = __float2bfloat16(f0.y);
      tmp[2] = __float2bfloat16(f0.z); tmp[3] = __float2bfloat16(f0.w);
      tmp[4] = __float2bfloat16(f1.x); tmp[5] = __float2bfloat16(f1.y);
      tmp[6] = __float2bfloat16(f1.z); tmp[7] = __float2bfloat16(f1.w);
      *(s16x8*)(xb + j * 8) = *(const s16x8*)tmp;
    }
  }
}

// ---------------------------------------------------------------------------
// Kernel 2: QKV projection GEMM. 128x128 tile, BK=32, LDS row stride 40
// (32 data + 8 pad; staged as 5x16B chunks/row, chunk 4 dups chunk 0) ->
// fragment ds_read_b128 start banks 2-way only (free, m136).
// Outputs: Qb [bh][s][64] (scaled 0.125*log2e), Kb [bh][s][64], Vt [bh][h][s].
// ---------------------------------------------------------------------------
#define GSTRIDE 40
__global__ __launch_bounds__(256) void qkv_gemm(
    const bf16* __restrict__ xb, const bf16* __restrict__ WcT,
    const float* __restrict__ bQ, const float* __restrict__ bK,
    const float* __restrict__ bV, bf16* __restrict__ Qb,
    bf16* __restrict__ Kb, bf16* __restrict__ Vt) {
  __shared__ bf16 As[128 * GSTRIDE];
  __shared__ bf16 Bs[128 * GSTRIDE];
  const int m0 = blockIdx.x * 128;
  const int n0 = blockIdx.y * 128;
  const int tid = threadIdx.x;
  const int wave = tid >> 6, lane = tid & 63;
  const int quad = lane >> 4, l15 = lane & 15;
  const int wm = (wave & 1) * 64, wn = (wave >> 1) * 64;

  f32x4 acc[4][4] = {};

  for (int k0 = 0; k0 < DM; k0 += 32) {
    // 640 chunks of 16B per matrix: 5 per 32-elem row (chunk 4 dups chunk 0)
    for (int u = 0; u < 3; u++) {
      int c = tid + u * 256;
      if (c < 640) {
        int row = c / 5;
        int i = c - row * 5;
        int off = (i & 3) << 3;  // i==4 -> 0 (dup into pad)
        gl2lds16(xb + (size_t)(m0 + row) * DM + k0 + off, &As[c * 8]);
        gl2lds16(WcT + (size_t)(n0 + row) * DM + k0 + off, &Bs[c * 8]);
      }
    }
    __syncthreads();
    s16x8 af[4], bfr[4];
    for (int i = 0; i < 4; i++)
      af[i] = *(const s16x8*)&As[(wm + i * 16 + l15) * GSTRIDE + quad * 8];
    for (int j = 0; j < 4; j++)
      bfr[j] = *(const s16x8*)&Bs[(wn + j * 16 + l15) * GSTRIDE + quad * 8];
    for (int i = 0; i < 4; i++)
      for (int j = 0; j < 4; j++)
        acc[i][j] = MFMA16(af[i], bfr[j], acc[i][j]);
    __syncthreads();
  }

  const int mat = n0 / DM;  // uniform per block (768 % 128 == 0)
  for (int j = 0; j < 4; j++) {
    int col = n0 + wn + j * 16 + l15;
    int cc = col - mat * DM;
    int head = cc >> 6, h = cc & 63;
    float bsv = ((mat == 0) ? bQ : (mat == 1) ? bK : bV)[cc];
    for (int i = 0; i < 4; i++) {
      int row0 = m0 + wm + i * 16 + quad * 4;
      int b = row0 >> 11;
      int s = row0 & 2047;
      int bh = b * NH + head;
      if (mat == 2) {
        s16x4 pv;
        for (int r = 0; r < 4; r++) {
          bf16 hv = __float2bfloat16(acc[i][j][r] + bsv);
          short sv; __builtin_memcpy(&sv, &hv, 2);
          pv[r] = sv;
        }
        *(s16x4*)(Vt + ((size_t)bh * DH + h) * SEQ + s) = pv;
      } else {
        const float scale = (mat == 0) ? (0.125f * LOG2E) : 1.0f;
        bf16* dst = ((mat == 0) ? Qb : Kb) + ((size_t)bh * SEQ + s) * DH + h;
        for (int r = 0; r < 4; r++)
          dst[(size_t)r * DH] = __float2bfloat16((acc[i][j][r] + bsv) * scale);
      }
    }
  }
}

// ---------------------------------------------------------------------------
// Kernel 3: flash attention (causal) — unchanged round-7 version.
// ---------------------------------------------------------------------------
__global__ __launch_bounds__(256) void flash_kernel(
    const bf16* __restrict__ Qb, const bf16* __restrict__ Kb,
    const bf16* __restrict__ Vt, bf16* __restrict__ Z) {
  __shared__ bf16 Ks[2][64 * 72];   // [key][h], stride 72
  __shared__ bf16 VsT[2][64 * 72];  // [h][key], stride 72
  __shared__ bf16 Ps[4][16 * 72];   // per-wave P [q][key], stride 72

  const int bh = blockIdx.x >> 4;  // 0..47
  const int p = blockIdx.x & 15;   // 0..15
  const int qtA = 31 - p, qtB = p;
  const int b = bh / NH, head = bh % NH;
  const int tid = threadIdx.x;
  const int wave = tid >> 6, lane = tid & 63;
  const int quad = lane >> 4, l15 = lane & 15;
  const int qwA = qtA * 64 + wave * 16;
  const int qwB = qtB * 64 + wave * 16;

  const bf16* Kbase = Kb + (size_t)bh * SEQ * DH;
  const bf16* Vbase = Vt + (size_t)bh * DH * SEQ;

  s16x8 bqA[2], bqB[2];
  for (int ks = 0; ks < 2; ks++) {
    bqA[ks] = *(const s16x8*)(Qb +
        ((size_t)bh * SEQ + qwA + l15) * DH + ks * 32 + quad * 8);
    bqB[ks] = *(const s16x8*)(Qb +
        ((size_t)bh * SEQ + qwB + l15) * DH + ks * 32 + quad * 8);
  }

  f32x4 oA[4] = {}, oB[4] = {};
  float lA = 0.f, lB = 0.f;

  auto stage_tile = [&](int kt, int buf) {
    const int kbase = kt * 64;
    for (int u = 0; u < 3; u++) {
      int c = tid + u * 256;
      if (c < 576) {
        int row = c / 9;
        int i = c - row * 9;
        int off = (i & 7) << 3;
        gl2lds16(Kbase + (size_t)(kbase + row) * DH + off, &Ks[buf][c * 8]);
        gl2lds16(Vbase + (size_t)row * SEQ + kbase + off, &VsT[buf][c * 8]);
      }
    }
  };

  auto compute = [&](int kt, int buf, const s16x8 bq[2], f32x4 o[4],
                     float& l_i, int qw, bool diag) {
    const int kbase = kt * 64;
    f32x4 s[4] = {};
    for (int ks = 0; ks < 2; ks++) {
      s16x8 ak[4];
      for (int ktf = 0; ktf < 4; ktf++)
        ak[ktf] =
            *(const s16x8*)&Ks[buf][(ktf * 16 + l15) * 72 + ks * 32 + quad * 8];
      for (int ktf = 0; ktf < 4; ktf++)
        s[ktf] = MFMA16(ak[ktf], bq[ks], s[ktf]);
    }

    if (diag) {
      int qg = qw + l15;
      for (int ktf = 0; ktf < 4; ktf++)
        for (int r = 0; r < 4; r++) {
          int kg = kbase + ktf * 16 + quad * 4 + r;
          if (kg > qg) s[ktf][r] = -1e30f;
        }
    }

    float rs = 0.f;
    for (int ktf = 0; ktf < 4; ktf++)
      for (int r = 0; r < 4; r++) {
        float pv = fast_exp2(s[ktf][r]);
        s[ktf][r] = pv;
        rs += pv;
      }
    l_i += rs;

    bf16* Pw = Ps[wave];
    for (int ktf = 0; ktf < 4; ktf++) {
      uint2 w;
      w.x = pkbf16(s[ktf][0], s[ktf][1]);
      w.y = pkbf16(s[ktf][2], s[ktf][3]);
      *(uint2*)&Pw[l15 * 72 + ktf * 16 + quad * 4] = w;
    }
    asm volatile("s_waitcnt lgkmcnt(0)" ::: "memory");

    for (int ks2 = 0; ks2 < 2; ks2++) {
      s16x8 ap = *(const s16x8*)&Pw[l15 * 72 + ks2 * 32 + quad * 8];
      for (int hf = 0; hf < 4; hf++) {
        s16x8 bv =
            *(const s16x8*)&VsT[buf][(hf * 16 + l15) * 72 + ks2 * 32 + quad * 8];
        o[hf] = MFMA16(ap, bv, o[hf]);
      }
    }
  };

  stage_tile(0, 0);
  for (int kt = 0; kt <= qtA; kt++) {
    const int cur = kt & 1;
    __syncthreads();
    if (kt < qtA) stage_tile(kt + 1, cur ^ 1);
    compute(kt, cur, bqA, oA, lA, qwA, kt == qtA);
    if (kt <= qtB) compute(kt, cur, bqB, oB, lB, qwB, kt == qtB);
  }

  auto epilogue = [&](f32x4 o[4], float l_i, int qw) {
    float lv = l_i;
    lv += __shfl_xor(lv, 16, 64);
    lv += __shfl_xor(lv, 32, 64);
    float linv = 1.f / lv;
    for (int r = 0; r < 4; r++) {
      float li = __shfl(linv, (lane & 48) | (quad * 4 + r), 64);
      int q = qw + quad * 4 + r;
      for (int hf = 0; hf < 4; hf++) {
        Z[((size_t)b * SEQ + q) * DM + head * DH + hf * 16 + l15] =
            __float2bfloat16(o[hf][r] * li);
      }
    }
  };
  epilogue(oA, lA, qwA);
  epilogue(oB, lB, qwB);
}

// ---------------------------------------------------------------------------
// Kernel 4: output projection. 128x128, BK=32, padded stride-40 LDS.
// ---------------------------------------------------------------------------
__global__ __launch_bounds__(256) void out_gemm(
    const bf16* __restrict__ Z, const bf16* __restrict__ WoT,
    const float* __restrict__ bO, float* __restrict__ out) {
  __shared__ bf16 As[128 * GSTRIDE];
  __shared__ bf16 Bs[128 * GSTRIDE];
  const int m0 = blockIdx.x * 128;
  const int n0 = blockIdx.y * 128;
  const int tid = threadIdx.x;
  const int wave = tid >> 6, lane = tid & 63;
  const int quad = lane >> 4, l15 = lane & 15;
  const int wm = (wave & 1) * 64, wn = (wave >> 1) * 64;

  f32x4 acc[4][4] = {};

  for (int k0 = 0; k0 < DM; k0 += 32) {
    for (int u = 0; u < 3; u++) {
      int c = tid + u * 256;
      if (c < 640) {
        int row = c / 5;
        int i = c - row * 5;
        int off = (i & 3) << 3;
        gl2lds16(Z + (size_t)(m0 + row) * DM + k0 + off, &As[c * 8]);
        gl2lds16(WoT + (size_t)(n0 + row) * DM + k0 + off, &Bs[c * 8]);
      }
    }
    __syncthreads();
    s16x8 af[4], bfr[4];
    for (int i = 0; i < 4; i++)
      af[i] = *(const s16x8*)&As[(wm + i * 16 + l15) * GSTRIDE + quad * 8];
    for (int j = 0; j < 4; j++)
      bfr[j] = *(const s16x8*)&Bs[(wn + j * 16 + l15) * GSTRIDE + quad * 8];
    for (int i = 0; i < 4; i++)
      for (int j = 0; j < 4; j++)
        acc[i][j] = MFMA16(af[i], bfr[j], acc[i][j]);
    __syncthreads();
  }

  for (int j = 0; j < 4; j++) {
    int col = n0 + wn + j * 16 + l15;
    float bv = bO[col];
    for (int i = 0; i < 4; i++)
      for (int r = 0; r < 4; r++) {
        int row = m0 + wm + i * 16 + quad * 4 + r;
        out[(size_t)row * DM + col] = acc[i][j][r] + bv;
      }
  }
}

// ---------------------------------------------------------------------------
extern "C" void kernel_launch(void* const* d_in, const int* in_sizes, int n_in,
                              void* d_out, int out_size, void* d_ws,
                              size_t ws_size, hipStream_t stream) {
  const float* x  = (const float*)d_in[0];
  const float* wq = (const float*)d_in[1];
  const float* wk = (const float*)d_in[2];
  const float* wv = (const float*)d_in[3];
  const float* wo = (const float*)d_in[4];
  const float* bq = (const float*)d_in[5];
  const float* bk = (const float*)d_in[6];
  const float* bv = (const float*)d_in[7];
  const float* bo = (const float*)d_in[8];
  float* out = (float*)d_out;

  bf16* WcT = (bf16*)d_ws;                    // 2304*768
  bf16* WoT = WcT + (size_t)QKVC * DM;        //  768*768
  bf16* Qb  = WoT + (size_t)DM * DM;          // 8192*768
  bf16* Kb  = Qb + (size_t)ROWS * DM;         // 8192*768
  bf16* Vt  = Kb + (size_t)ROWS * DM;         // 8192*768 ([bh][h][s])
  bf16* xbZ = Vt + (size_t)ROWS * DM;         // 8192*768 (xb, then Z)

  prep_all<<<PREP_C, 256, 0, stream>>>(wq, wk, wv, wo, x, WcT, WoT, xbZ);
  qkv_gemm<<<dim3(ROWS / 128, QKVC / 128), 256, 0, stream>>>(
      xbZ, WcT, bq, bk, bv, Qb, Kb, Vt);
  flash_kernel<<<48 * 16, 256, 0, stream>>>(Qb, Kb, Vt, xbZ);
  out_gemm<<<dim3(ROWS / 128, DM / 128), 256, 0, stream>>>(xbZ, WoT, bo, out);
}